// Round 12
// baseline (76.601 us; speedup 1.0000x reference)
//
#include <hip/hip_runtime.h>

typedef int   int4v  __attribute__((ext_vector_type(4)));
typedef char  char8v __attribute__((ext_vector_type(8)));

#define NROWS 8192
#define DIM 512

#define AS1(p) ((const __attribute__((address_space(1))) void*)(p))
#define AS3(p) ((__attribute__((address_space(3))) void*)(p))

#if __has_builtin(__builtin_amdgcn_exp2f)
#define EXP2(x) __builtin_amdgcn_exp2f(x)
#else
#define EXP2(x) exp2f(x)
#endif

// ---------------------------------------------------------------------------
// Kernel 1: wave-per-row normalize + i8 quantize + diag. BOTH operands are
// written PACKED in MFMA-fragment order (layout correctness-proven R10/R11):
//   frag (rowgrp g = row/16, kstep t = k/128, half kk = (k/64)&1) is 1024 B
//   at g*8192 + t*2048 + kk*1024; consuming lane l holds row g*16+(l&15),
//   k-bytes t*128 + kk*64 + (l>>4)*16.
// No rowsum zeroing needed (R12 epilogue uses store-once partials, no atomics).
// ---------------------------------------------------------------------------
__global__ __launch_bounds__(256) void prep_kernel(
    const float* __restrict__ v, const float* __restrict__ u,
    char* __restrict__ vpack, char* __restrict__ upack,
    float* __restrict__ sa, float* __restrict__ sb,
    float* __restrict__ diag)
{
    const int row  = blockIdx.x * 4 + (threadIdx.x >> 6);
    const int lane = threadIdx.x & 63;
    const float4* vr = reinterpret_cast<const float4*>(v + (size_t)row * DIM);
    const float4* ur = reinterpret_cast<const float4*>(u + (size_t)row * DIM);
    const float4 a0 = vr[lane * 2], a1 = vr[lane * 2 + 1];
    const float4 b0 = ur[lane * 2], b1 = ur[lane * 2 + 1];
    float av[8] = {a0.x, a0.y, a0.z, a0.w, a1.x, a1.y, a1.z, a1.w};
    float bv[8] = {b0.x, b0.y, b0.z, b0.w, b1.x, b1.y, b1.z, b1.w};
    float sv = 0.f, su = 0.f, sd = 0.f, mv = 0.f, mu = 0.f;
#pragma unroll
    for (int i = 0; i < 8; ++i) {
        sv += av[i] * av[i];
        su += bv[i] * bv[i];
        sd += av[i] * bv[i];
        mv = fmaxf(mv, fabsf(av[i]));
        mu = fmaxf(mu, fabsf(bv[i]));
    }
#pragma unroll
    for (int m = 32; m; m >>= 1) {
        sv += __shfl_xor(sv, m);
        su += __shfl_xor(su, m);
        sd += __shfl_xor(sd, m);
        mv = fmaxf(mv, __shfl_xor(mv, m));
        mu = fmaxf(mu, __shfl_xor(mu, m));
    }
    const float rv = 1.0f / fmaxf(sqrtf(sv), 1e-8f);
    const float ru = 1.0f / fmaxf(sqrtf(su), 1e-8f);
    const float qv = 127.0f / fmaxf(mv, 1e-20f);
    const float qu = 127.0f / fmaxf(mu, 1e-20f);
    char8v cv, cu;
#pragma unroll
    for (int i = 0; i < 8; ++i) {
        cv[i] = (char)__float2int_rn(av[i] * qv);
        cu[i] = (char)__float2int_rn(bv[i] * qu);
    }
    const size_t dst = (size_t)(row >> 4) * 8192 + (lane >> 4) * 2048 +
                       ((lane >> 3) & 1) * 1024 +
                       ((((lane >> 1) & 3) * 16 + (row & 15)) * 16) +
                       (lane & 1) * 8;
    *reinterpret_cast<char8v*>(vpack + dst) = cv;
    *reinterpret_cast<char8v*>(upack + dst) = cu;
    if (lane == 0) {
        sa[row] = mv * rv / 127.0f;
        sb[row] = mu * ru / 127.0f;
        diag[row] = sd * rv * ru;
    }
}

// ---------------------------------------------------------------------------
// Kernel 2: BARRIER-FREE i8 GEMM + fused exp2 partial rowsum.
// R7/R9/R11 lesson: every barrier-per-K-step variant is stall-bound at
// 43-57us with all pipes <35%. Here the block's B (64 cols x full K=512,
// fragment-packed) is staged to LDS ONCE (8 gloads/thread, one sync), then
// the K-loop is a pure stream: A-frags from L2 (Apack, coalesced lane*16,
// prefetched one K-step ahead into named A0/A1 - rule #20), B-frags from
// LDS at frag_base+lane*16 (contiguous -> conflict-free, no swizzle).
// Zero barriers, 16 independent MFMA chains -> scheduler pipelines freely.
// Wave = 64 rows x 64 cols (acc[4][4]=64 regs); block = 4 waves = 256 rows.
// Grid 32 x 128. LDS reads: 512 MB total (halved vs R7/R9). Epilogue:
// store-once partials rowsum2d[cb][row] (no atomics).
// ---------------------------------------------------------------------------
__global__ __launch_bounds__(256) void simsum_kernel(
    const char* __restrict__ Apack, const char* __restrict__ Bpack,
    const float* __restrict__ sa, const float* __restrict__ sb,
    float* __restrict__ rowsum2d)
{
    __shared__ __align__(16) char ldsB[32768];   // 64 cols x K512, frag order
    const int tid  = threadIdx.x;
    const int wave = tid >> 6;
    const int lane = tid & 63;
    const int ln15 = lane & 15;
    const int lhi  = lane >> 4;

    const int rb = blockIdx.x;                 // 0..31  -> 256 rows
    const int cb = blockIdx.y;                 // 0..127 -> 64 cols
    const int grow = rb * 256 + wave * 64;     // this wave's 64 rows
    const char* abase = Apack + (size_t)(grow >> 4) * 8192;
    const char* bbase = Bpack + (size_t)cb * 32768;

    // ---- stage B once: 32 KB linear copy (frag order preserved) ----
#pragma unroll
    for (int i = 0; i < 8; ++i)
        __builtin_amdgcn_global_load_lds(
            AS1(bbase + i * 4096 + tid * 16),
            AS3(ldsB + i * 4096 + tid * 16), 16, 0, 0);
    __syncthreads();   // the ONLY barrier

    int4v acc[4][4];
#pragma unroll
    for (int m = 0; m < 4; ++m)
#pragma unroll
        for (int n = 0; n < 4; ++n)
            acc[m][n] = (int4v){0, 0, 0, 0};

    // frag offset for K-step ks: (ks>>1)*2048 + (ks&1)*1024 + lane*16
#define KOFF(KS) ((size_t)((KS) >> 1) * 2048 + ((KS) & 1) * 1024 + lane * 16)
#define LDA(DST, KS) do {                                                     \
    _Pragma("unroll") for (int m_ = 0; m_ < 4; ++m_)                          \
        DST[m_] = *reinterpret_cast<const int4v*>(                            \
            abase + (size_t)m_ * 8192 + KOFF(KS));                            \
    } while (0)
#define STEP(AA, KS) do {                                                     \
    int4v Bf_[4];                                                             \
    _Pragma("unroll") for (int n_ = 0; n_ < 4; ++n_)                          \
        Bf_[n_] = *reinterpret_cast<const int4v*>(ldsB + n_ * 8192 + KOFF(KS));\
    _Pragma("unroll") for (int m_ = 0; m_ < 4; ++m_)                          \
    _Pragma("unroll") for (int n_ = 0; n_ < 4; ++n_)                          \
        acc[m_][n_] = __builtin_amdgcn_mfma_i32_16x16x64_i8(                  \
            AA[m_], Bf_[n_], acc[m_][n_], 0, 0, 0);                           \
    } while (0)

    int4v A0[4], A1[4];
    LDA(A0, 0);
#pragma unroll
    for (int kp = 0; kp < 4; ++kp) {
        LDA(A1, kp * 2 + 1);              // prefetch next while computing
        STEP(A0, kp * 2);
        if (kp < 3) LDA(A0, kp * 2 + 2);
        STEP(A1, kp * 2 + 1);
    }

    // ---- epilogue: partial rowsum over this block's 64 cols ----
    // C/D layout: col = lane&15, row = (lane>>4)*4 + reg  [m89/m91 verified]
    const float C2 = 2.885390081777927f;   // 2 * log2(e)
    float sbv[4];
#pragma unroll
    for (int n = 0; n < 4; ++n)
        sbv[n] = sb[cb * 64 + n * 16 + ln15];
#pragma unroll
    for (int m = 0; m < 4; ++m) {
#pragma unroll
        for (int rr = 0; rr < 4; ++rr) {
            const float g = sa[grow + m * 16 + lhi * 4 + rr] * C2;
            float s = 0.f;
#pragma unroll
            for (int n = 0; n < 4; ++n)
                s += EXP2((float)acc[m][n][rr] * g * sbv[n]);
            s += __shfl_xor(s, 1);
            s += __shfl_xor(s, 2);
            s += __shfl_xor(s, 4);
            s += __shfl_xor(s, 8);
            if (ln15 == 0)
                rowsum2d[(size_t)cb * NROWS + grow + m * 16 + lhi * 4 + rr] = s;
        }
    }
#undef KOFF
#undef LDA
#undef STEP
}

// ---------------------------------------------------------------------------
// Kernel 3: loss_i = log(exp(2*diag_i) + sum_j partials[j][i]) - 2*diag_i
// ---------------------------------------------------------------------------
__global__ __launch_bounds__(256) void loss_kernel(
    const float* __restrict__ diag, const float* __restrict__ rowsum2d,
    float* __restrict__ out)
{
    const int i = blockIdx.x * 256 + threadIdx.x;
    float acc = 0.f;
#pragma unroll 8
    for (int j = 0; j < 128; ++j)
        acc += rowsum2d[(size_t)j * NROWS + i];   // coalesced across i
    const float d2 = diag[i] * 2.0f;
    out[i] = logf(expf(d2) + acc) - d2;
}

extern "C" void kernel_launch(void* const* d_in, const int* in_sizes, int n_in,
                              void* d_out, int out_size, void* d_ws, size_t ws_size,
                              hipStream_t stream) {
    const float* v = (const float*)d_in[0];
    const float* u = (const float*)d_in[1];
    float* out = (float*)d_out;
    char* ws = (char*)d_ws;
    char*  vpack    = ws;                                   // 4 MiB
    char*  upack    = ws + (size_t)4194304;                 // 4 MiB
    float* rowsum2d = (float*)(ws + (size_t)8388608);       // 4 MiB [128][8192]
    float* sa       = (float*)(ws + (size_t)12582912);      // 32 KiB
    float* sb       = (float*)(ws + (size_t)12582912 + 32768);
    float* diag     = (float*)(ws + (size_t)12582912 + 65536);

    prep_kernel<<<NROWS / 4, 256, 0, stream>>>(v, u, vpack, upack, sa, sb, diag);
    dim3 grid(32, 128);
    simsum_kernel<<<grid, 256, 0, stream>>>(vpack, upack, sa, sb, rowsum2d);
    loss_kernel<<<NROWS / 256, 256, 0, stream>>>(diag, rowsum2d, out);
}

// Round 13
// 52.503 us; speedup vs baseline: 1.4590x; 1.4590x over previous
//
#include <hip/hip_runtime.h>

typedef int   int4v  __attribute__((ext_vector_type(4)));
typedef char  char8v __attribute__((ext_vector_type(8)));

#define NROWS 8192
#define DIM 512
#define ROWB 512           // DIM * 1 byte (i8)
#define NT 4               // K-steps of BK=128 per col-tile
#define SWEEP 8            // col-tiles of 128 per block (R7 geometry)

#define AS1(p) ((const __attribute__((address_space(1))) void*)(p))
#define AS3(p) ((__attribute__((address_space(3))) void*)(p))

#if __has_builtin(__builtin_amdgcn_exp2f)
#define EXP2(x) __builtin_amdgcn_exp2f(x)
#else
#define EXP2(x) exp2f(x)
#endif

// ---------------------------------------------------------------------------
// Kernel 1: wave-per-row normalize + i8 quantize + diag + rowsum zero.
// (identical to R7/R9 — proven)
// ---------------------------------------------------------------------------
__global__ __launch_bounds__(256) void prep_kernel(
    const float* __restrict__ v, const float* __restrict__ u,
    char* __restrict__ vq, char* __restrict__ uq,
    float* __restrict__ sa, float* __restrict__ sb,
    float* __restrict__ diag, float* __restrict__ rowsum)
{
    const int row  = blockIdx.x * 4 + (threadIdx.x >> 6);
    const int lane = threadIdx.x & 63;
    const float4* vr = reinterpret_cast<const float4*>(v + (size_t)row * DIM);
    const float4* ur = reinterpret_cast<const float4*>(u + (size_t)row * DIM);
    const float4 a0 = vr[lane * 2], a1 = vr[lane * 2 + 1];
    const float4 b0 = ur[lane * 2], b1 = ur[lane * 2 + 1];
    float av[8] = {a0.x, a0.y, a0.z, a0.w, a1.x, a1.y, a1.z, a1.w};
    float bv[8] = {b0.x, b0.y, b0.z, b0.w, b1.x, b1.y, b1.z, b1.w};
    float sv = 0.f, su = 0.f, sd = 0.f, mv = 0.f, mu = 0.f;
#pragma unroll
    for (int i = 0; i < 8; ++i) {
        sv += av[i] * av[i];
        su += bv[i] * bv[i];
        sd += av[i] * bv[i];
        mv = fmaxf(mv, fabsf(av[i]));
        mu = fmaxf(mu, fabsf(bv[i]));
    }
#pragma unroll
    for (int m = 32; m; m >>= 1) {
        sv += __shfl_xor(sv, m);
        su += __shfl_xor(su, m);
        sd += __shfl_xor(sd, m);
        mv = fmaxf(mv, __shfl_xor(mv, m));
        mu = fmaxf(mu, __shfl_xor(mu, m));
    }
    const float rv = 1.0f / fmaxf(sqrtf(sv), 1e-8f);
    const float ru = 1.0f / fmaxf(sqrtf(su), 1e-8f);
    const float qv = 127.0f / fmaxf(mv, 1e-20f);
    const float qu = 127.0f / fmaxf(mu, 1e-20f);
    char8v cv, cu;
#pragma unroll
    for (int i = 0; i < 8; ++i) {
        cv[i] = (char)__float2int_rn(av[i] * qv);
        cu[i] = (char)__float2int_rn(bv[i] * qu);
    }
    reinterpret_cast<char8v*>(vq + (size_t)row * DIM)[lane] = cv;
    reinterpret_cast<char8v*>(uq + (size_t)row * DIM)[lane] = cu;
    if (lane == 0) {
        sa[row] = mv * rv / 127.0f;
        sb[row] = mu * ru / 127.0f;
        diag[row] = sd * rv * ru;
        rowsum[row] = 0.0f;
    }
}

// ---------------------------------------------------------------------------
// Kernel 2: R7's exact A-stationary geometry (best measured: 43.5us) with the
// ONLY change being the staging schedule: 4-deep LDS ring, depth-2 prefetch,
// raw s_barrier + counted vmcnt(4) per step (T3/T4) instead of __syncthreads'
// vmcnt(0) drain — R7's measured ~1630 cyc/step vs ~350 cyc of work was the
// barrier drain of the just-issued next-tile gloads (L2/HBM 200-900 cyc).
//
// Ring schedule, 32 global steps g = s*4+tt (buffer g&3 == tt&3, compile-time):
//   prologue: stage(0), stage(1), vmcnt(4) [g0 landed], barrier
//   step g: stage g+2 -> buf (tt+2)&3   [buffer last read at g-2, 2 barriers ago]
//           compute from buf tt&3 (16 ds_read_b128, 32 MFMA, XOR-swizzled)
//           g<30: vmcnt(4)  [drains exactly g+1's 4 loads; g+2's stay in flight]
//           g==30: vmcnt(0); g<31: s_barrier (raw, no drain)
// ---------------------------------------------------------------------------
__global__ __launch_bounds__(256, 2) void simsum_kernel(
    const char* __restrict__ A, const char* __restrict__ Bq,
    const float* __restrict__ sa, const float* __restrict__ sb,
    float* __restrict__ rowsum)
{
    __shared__ __align__(16) char ldsB[4][16384];  // ring: 4 x (128 cols x 128 B)
    const int tid  = threadIdx.x;
    const int wave = tid >> 6;
    const int lane = tid & 63;
    const int ln15 = lane & 15;
    const int lhi  = lane >> 4;
    const int swz  = (ln15 & 7) << 4;          // read-side XOR (= col&7 <<4)

    const int brow = blockIdx.x;               // 0..63 -> 128 rows each
    const int bgrp = blockIdx.y;               // 0..7  -> 8 col-tiles of 128
    const int growA = brow * 128 + wave * 32;  // this wave's 32 rows
    const int gcol0 = bgrp * (SWEEP * 128);    // this block's 1024 cols

    const char* gA = A;
    const char* gB = Bq;

    // ---- A into registers: [t][kk][m], 16 x int4v = 64 VGPR (R7 proven) ----
    int4v Areg[NT][2][2];
#pragma unroll
    for (int t = 0; t < NT; ++t)
#pragma unroll
        for (int kk = 0; kk < 2; ++kk)
#pragma unroll
            for (int m = 0; m < 2; ++m) {
                const int r = growA + m * 16 + ln15;
                Areg[t][kk][m] = *reinterpret_cast<const int4v*>(
                    gA + (size_t)r * ROWB + t * 128 + kk * 64 + lhi * 16);
            }

    // per-row dequant scale (x 2*log2e) for this thread's 8 rows
    const float C2 = 2.885390081777927f;   // 2 * log2(e)
    float ga[2][4];
#pragma unroll
    for (int m = 0; m < 2; ++m)
#pragma unroll
        for (int rr = 0; rr < 4; ++rr)
            ga[m][rr] = sa[growA + m * 16 + lhi * 4 + rr] * C2;

    float rs[2][4];
#pragma unroll
    for (int m = 0; m < 2; ++m)
#pragma unroll
        for (int rr = 0; rr < 4; ++rr)
            rs[m][rr] = 0.f;

    // staging: 4 gloads/thread cover one 16 KB col-tile-K-step; linear LDS
    // dest, source k-chunk pre-swizzled (G21 both-sides pairing, 0-conflict).
    const int r0   = tid >> 3;
    const int sl16 = (((tid & 7) ^ ((tid >> 3) & 7)) << 4);

    auto stageB = [&](int bi, int gs) {       // gs = global step 0..31
        const int ct = gs >> 2;               // col-tile 0..7
        const int kt = gs & 3;                // K-step 0..3
#pragma unroll
        for (int q = 0; q < 4; ++q) {
            const int col = gcol0 + ct * 128 + q * 32 + r0;
            __builtin_amdgcn_global_load_lds(
                AS1(gB + (size_t)col * ROWB + kt * 128 + sl16),
                AS3(&ldsB[bi][q * 4096 + tid * 16]), 16, 0, 0);
        }
    };

    // ---- prologue: depth-2 ----
    stageB(0, 0);
    stageB(1, 1);
    asm volatile("s_waitcnt vmcnt(4)" ::: "memory");   // step 0 landed
    asm volatile("s_barrier" ::: "memory");

    for (int s = 0; s < SWEEP; ++s) {
        int4v acc[2][8];
#pragma unroll
        for (int m = 0; m < 2; ++m)
#pragma unroll
            for (int n = 0; n < 8; ++n)
                acc[m][n] = (int4v){0, 0, 0, 0};

#pragma unroll
        for (int tt = 0; tt < NT; ++tt) {
            const int g = s * 4 + tt;
            if (g + 2 < 32) stageB((tt + 2) & 3, g + 2);
#pragma unroll
            for (int kk = 0; kk < 2; ++kk) {
                int4v Bf[8];
#pragma unroll
                for (int n = 0; n < 8; ++n) {
                    const int c = n * 16 + ln15;
                    Bf[n] = *reinterpret_cast<const int4v*>(
                        &ldsB[tt & 3][c * 128 + ((kk * 64 + lhi * 16) ^ swz)]);
                }
#pragma unroll
                for (int m = 0; m < 2; ++m)
#pragma unroll
                    for (int n = 0; n < 8; ++n)
                        acc[m][n] = __builtin_amdgcn_mfma_i32_16x16x64_i8(
                            Areg[tt][kk][m], Bf[n], acc[m][n], 0, 0, 0);
            }
            // counted wait: g+1's 4 loads drained, g+2's stay in flight
            if (g < 30)       asm volatile("s_waitcnt vmcnt(4)" ::: "memory");
            else if (g == 30) asm volatile("s_waitcnt vmcnt(0)" ::: "memory");
            if (g < 31)       asm volatile("s_barrier" ::: "memory");
        }

        // fused epilogue for this 128-col tile: lane-local partial row sums
        float sbv[8];
#pragma unroll
        for (int n = 0; n < 8; ++n)
            sbv[n] = sb[gcol0 + s * 128 + n * 16 + ln15];
#pragma unroll
        for (int m = 0; m < 2; ++m)
#pragma unroll
            for (int rr = 0; rr < 4; ++rr) {
                const float g2 = ga[m][rr];
#pragma unroll
                for (int n = 0; n < 8; ++n)
                    rs[m][rr] += EXP2((float)acc[m][n][rr] * g2 * sbv[n]);
            }
    }

    // final cross-lane reduce (cols live across ln15) + one atomic per row
#pragma unroll
    for (int m = 0; m < 2; ++m)
#pragma unroll
        for (int rr = 0; rr < 4; ++rr) {
            float s = rs[m][rr];
            s += __shfl_xor(s, 1);
            s += __shfl_xor(s, 2);
            s += __shfl_xor(s, 4);
            s += __shfl_xor(s, 8);
            if (ln15 == 0)
                atomicAdd(&rowsum[growA + m * 16 + lhi * 4 + rr], s);
        }
}

// ---------------------------------------------------------------------------
// Kernel 3: loss_i = log(exp(2*diag_i) + rowsum_i) - 2*diag_i
// ---------------------------------------------------------------------------
__global__ __launch_bounds__(256) void loss_kernel(
    const float* __restrict__ diag, const float* __restrict__ rowsum,
    float* __restrict__ out)
{
    const int i = blockIdx.x * 256 + threadIdx.x;
    const float d2 = diag[i] * 2.0f;
    out[i] = logf(expf(d2) + rowsum[i]) - d2;
}

extern "C" void kernel_launch(void* const* d_in, const int* in_sizes, int n_in,
                              void* d_out, int out_size, void* d_ws, size_t ws_size,
                              hipStream_t stream) {
    const float* v = (const float*)d_in[0];
    const float* u = (const float*)d_in[1];
    float* out = (float*)d_out;
    char* ws = (char*)d_ws;
    char*  vq     = ws;                                   // 4 MiB
    char*  uq     = ws + (size_t)4194304;                 // 4 MiB
    float* sa     = (float*)(ws + (size_t)8388608);       // 32 KiB
    float* sb     = (float*)(ws + (size_t)8388608 + 32768);
    float* diag   = (float*)(ws + (size_t)8388608 + 65536);
    float* rowsum = (float*)(ws + (size_t)8388608 + 98304);

    prep_kernel<<<NROWS / 4, 256, 0, stream>>>(v, u, vq, uq, sa, sb, diag, rowsum);
    dim3 grid(64, 8);
    simsum_kernel<<<grid, 256, 0, stream>>>(vq, uq, sa, sb, rowsum);
    loss_kernel<<<NROWS / 256, 256, 0, stream>>>(diag, rowsum, out);
}